// Round 6
// baseline (338.480 us; speedup 1.0000x reference)
//
#include <hip/hip_runtime.h>
#include <stdint.h>

#define HV 384
#define WV 384
#define HF 96
#define WF 96
#define NC 128
#define NB 32
#define NSTORM 50
#define TFRAMES 12
#define MIN_INT 0.3f

// peak tile geometry
#define TW 64
#define TH 32
#define GX (WV / TW)          // 6
#define GY (HV / TH)          // 12
#define GT (GX * GY)          // 72 tiles per batch
#define LCAP 256              // >= max real peaks per tile (~60 observed)

// selection
#define SELCAP 2048
#define SSZ 8                 // keys per thread list
#define LSTR 9                // list stride in u64 (8 + pad)

__device__ __forceinline__ int reflect_idx(int g, int n) {
    if (g < 0) return -g - 1;
    if (g >= n) return 2 * n - 1 - g;
    return g;
}

// ---- slow scalar peak predicate, used only on the dead fallback path
__device__ __forceinline__ bool is_peak(const float* __restrict__ vb, int p) {
    int i = p / WV, j = p % WV;
    float v = vb[p];
    if (!(v > MIN_INT)) return false;
    for (int dr = -4; dr <= 3; ++dr) {
        const float* row = vb + reflect_idx(i + dr, HV) * WV;
        for (int dc = -4; dc <= 3; ++dc)
            if (row[reflect_idx(j + dc, WV)] > v) return false;
    }
    return true;
}

// ---- kernel 1: separable 8x8 max filter on LDS tiles; float4 staging;
// per-tile candidate slots (no global atomics, no memset — every tcnt slot
// is written every launch). key = (float_bits(v) << 32) | ~idx — strict
// total order -> deterministic selection regardless of compaction order.
__global__ void peak_kernel(const float* __restrict__ vil,
                            uint64_t* __restrict__ cand,
                            int* __restrict__ tcnt) {
    __shared__ __align__(16) float A[TH + 7][TW + 8];  // tile + halo
    __shared__ float Bm[TH + 7][TW];                   // horizontal max
    __shared__ uint64_t lkeys[LCAP];
    __shared__ int lcnt;

    int b = blockIdx.z, bx = blockIdx.x;
    int tx0 = bx * TW, ty0 = blockIdx.y * TH;
    int tile = blockIdx.y * GX + bx;
    int tid = threadIdx.x;                 // 256 threads
    const float* vb = vil + ((size_t)b * TFRAMES + (TFRAMES - 1)) * (HV * WV);

    if (tid == 0) lcnt = 0;

    // float4 staging; row reflect is pointer-only, keeps 16B alignment.
    int c0   = (bx == 0) ? 0 : tx0 - 4;               // multiple of 4
    int nf4  = (bx == 0 || bx == GX - 1) ? 17 : 18;
    int aoff = c0 - (tx0 - 4);                        // 0 or 4
    for (int k = tid; k < (TH + 7) * nf4; k += 256) {
        int r = k / nf4, q = k - r * nf4;
        int gr = reflect_idx(ty0 + r - 4, HV);
        float4 vv = *(const float4*)(vb + (size_t)gr * WV + c0 + 4 * q);
        *(float4*)&A[r][aoff + 4 * q] = vv;
    }
    int nl = aoff;
    int rstart = aoff + 4 * nf4;
    int nr = 71 - rstart; if (nr < 0) nr = 0;
    int ns = nl + nr;
    if (ns) for (int k = tid; k < (TH + 7) * ns; k += 256) {
        int r = k / ns, s = k - r * ns;
        int c = (s < nl) ? s : rstart + (s - nl);
        int gr = reflect_idx(ty0 + r - 4, HV);
        int gc = reflect_idx(tx0 + c - 4, WV);
        A[r][c] = vb[(size_t)gr * WV + gc];
    }
    __syncthreads();

    // horizontal: Bm[r][c] = max(A[r][c..c+7])
    for (int k = tid; k < (TH + 7) * TW; k += 256) {
        int r = k / TW, c = k % TW;
        float m = A[r][c];
        #pragma unroll
        for (int d = 1; d < 8; ++d) m = fmaxf(m, A[r][c + d]);
        Bm[r][c] = m;
    }
    __syncthreads();

    // vertical + predicate
    for (int k = tid; k < TH * TW; k += 256) {
        int r = k / TW, c = k % TW;
        float v = A[r + 4][c + 4];
        if (v > MIN_INT) {
            float m = Bm[r][c];
            #pragma unroll
            for (int d = 1; d < 8; ++d) m = fmaxf(m, Bm[r + d][c]);
            if (m <= v) {                  // window max == v -> peak
                int p = (ty0 + r) * WV + (tx0 + c);
                uint64_t key = ((uint64_t)__float_as_uint(v) << 32)
                             | (uint64_t)(0xFFFFFFFFu - (uint32_t)p);
                int pos = atomicAdd(&lcnt, 1);        // LDS atomic only
                if (pos < LCAP) lkeys[pos] = key;
            }
        }
    }
    __syncthreads();

    int take = lcnt < LCAP ? lcnt : LCAP;
    if (tid == 0) tcnt[b * GT + tile] = take;
    uint64_t* dst = cand + (size_t)(b * GT + tile) * LCAP;
    for (int k = tid; k < take; k += 256) dst[k] = lkeys[k];
}

// ---- kernel 2: per batch, top-50 (desc value, ties -> lower idx).
// Parallel scan of tile counts; per-thread insertion sort of an 8-key chunk
// of the virtual concatenation; single-wave 256-way merge (4 lists/lane).
// Also emits node_positions and valid (tiny writes).
__global__ void select_kernel(const uint64_t* __restrict__ cand,
                              const int* __restrict__ tcnt,
                              const float* __restrict__ vil,
                              int* __restrict__ sel_idx,
                              int* __restrict__ sel_valid,
                              float* __restrict__ out) {
    __shared__ uint64_t lists[256 * LSTR];     // 18 KB
    __shared__ int sc[128];
    __shared__ int offs[GT + 1];
    __shared__ int sel_idx_s[NSTORM];
    __shared__ int sel_valid_s[NSTORM];
    __shared__ uint64_t wred[4];
    __shared__ uint64_t bcast;

    int b = blockIdx.x;
    int tid = threadIdx.x;                     // 256
    const uint64_t* cb = cand + (size_t)b * GT * LCAP;

    // Hillis-Steele inclusive scan of 72 counts (padded to 128)
    int cval = (tid < GT) ? tcnt[b * GT + tid] : 0;
    if (tid < 128) sc[tid] = cval;
    __syncthreads();
    #pragma unroll
    for (int off = 1; off < 128; off <<= 1) {
        int v = 0;
        if (tid < 128 && tid >= off) v = sc[tid - off];
        __syncthreads();
        if (tid < 128) sc[tid] += v;
        __syncthreads();
    }
    if (tid == 0) offs[0] = 0;
    if (tid < GT) offs[tid + 1] = sc[tid];
    __syncthreads();
    int n = offs[GT];
    int K = n < NSTORM ? n : NSTORM;

    if (n <= SELCAP) {
        // insertion-sort my 8-key chunk (binary search over tile offsets)
        int base = tid * LSTR, len = 0;
        for (int a = 0; a < SSZ; ++a) {
            int gi = tid * SSZ + a;
            uint64_t key = 0;
            if (gi < n) {
                int lo = 0, hi = GT;
                while (hi - lo > 1) { int mid = (lo + hi) >> 1;
                                      if (offs[mid] <= gi) lo = mid; else hi = mid; }
                key = cb[(size_t)lo * LCAP + (gi - offs[lo])];
            }
            int j = len - 1;
            while (j >= 0 && lists[base + j] < key) {
                lists[base + j + 1] = lists[base + j]; --j;
            }
            lists[base + j + 1] = key; ++len;
        }
        __syncthreads();
        // single-wave 256-way merge: lane owns 4 lists; keys unique, 0=sentinel
        if (tid < 64) {
            uint64_t v[4]; int h[4];
            #pragma unroll
            for (int i = 0; i < 4; ++i) { h[i] = 0; v[i] = lists[(tid * 4 + i) * LSTR]; }
            for (int t = 0; t < K; ++t) {
                uint64_t best = v[0];
                #pragma unroll
                for (int i = 1; i < 4; ++i) if (v[i] > best) best = v[i];
                #pragma unroll
                for (int off = 32; off > 0; off >>= 1) {
                    uint64_t o = __shfl_xor(best, off);
                    if (o > best) best = o;
                }
                #pragma unroll
                for (int i = 0; i < 4; ++i) {
                    if (v[i] == best) {
                        ++h[i];
                        v[i] = (h[i] < SSZ) ? lists[(tid * 4 + i) * LSTR + h[i]] : 0;
                    }
                }
                if (tid == 0) {
                    sel_idx_s[t] = (int)(~(uint32_t)(best & 0xFFFFFFFFu));
                    sel_valid_s[t] = 1;
                }
            }
        }
    } else {
        // dead safety path (n > 2048): iterative rescan via binary search
        uint64_t prev = ~0ull;
        for (int t = 0; t < K; ++t) {
            uint64_t best = 0;
            for (int gi = tid; gi < n; gi += 256) {
                int lo = 0, hi = GT;
                while (hi - lo > 1) { int mid = (lo + hi) >> 1;
                                      if (offs[mid] <= gi) lo = mid; else hi = mid; }
                uint64_t key = cb[(size_t)lo * LCAP + (gi - offs[lo])];
                if (key < prev && key > best) best = key;
            }
            #pragma unroll
            for (int off = 32; off > 0; off >>= 1) {
                uint64_t o = __shfl_xor(best, off);
                if (o > best) best = o;
            }
            if ((tid & 63) == 0) wred[tid >> 6] = best;
            __syncthreads();
            if (tid == 0) {
                uint64_t w = wred[0];
                #pragma unroll
                for (int i = 1; i < 4; ++i) if (wred[i] > w) w = wred[i];
                bcast = w;
                sel_idx_s[t] = (int)(~(uint32_t)(w & 0xFFFFFFFFu));
                sel_valid_s[t] = 1;
            }
            __syncthreads();
            prev = bcast;
        }
    }
    __syncthreads();

    // dead fallback: <50 peaks -> ascending non-peak indices; none -> center
    if (tid == 0 && K < NSTORM) {
        const float* vb = vil + ((size_t)b * TFRAMES + (TFRAMES - 1)) * (HV * WV);
        int f = 0;
        for (int t = K; t < NSTORM; ++t) {
            while (f < HV * WV && is_peak(vb, f)) ++f;
            sel_idx_s[t] = f; sel_valid_s[t] = 0; ++f;
        }
        if (n == 0) { sel_idx_s[0] = (HV / 2) * WV + (WV / 2); sel_valid_s[0] = 1; }
    }
    __syncthreads();

    if (tid < NSTORM) {
        int idx = sel_idx_s[tid], vld = sel_valid_s[tid];
        sel_idx[b * NSTORM + tid] = idx;
        sel_valid[b * NSTORM + tid] = vld;
        int y = idx / WV, x = idx % WV;
        int yf = y >> 2; if (yf > HF - 1) yf = HF - 1;
        int xf = x >> 2; if (xf > WF - 1) xf = WF - 1;
        float* pos_out   = out + (size_t)NB * NSTORM * NC;
        float* valid_out = pos_out + (size_t)NB * NSTORM * 2;
        pos_out[(b * NSTORM + tid) * 2 + 0] = (float)yf;
        pos_out[(b * NSTORM + tid) * 2 + 1] = (float)xf;
        valid_out[b * NSTORM + tid] = vld ? 1.f : 0.f;
    }
}

// ---- kernel 3: gather feature column + 128x128 matvec + bias (1600 blocks)
__global__ void project_kernel(const float* __restrict__ features,
                               const float* __restrict__ proj_w,
                               const float* __restrict__ proj_b,
                               const int* __restrict__ sel_idx,
                               const int* __restrict__ sel_valid,
                               float* __restrict__ out) {
    int blk = blockIdx.x;
    int b = blk / NSTORM;
    int m = blk % NSTORM;
    int tid = threadIdx.x;                 // 0..127

    int idx = sel_idx[b * NSTORM + m];
    int vld = sel_valid[b * NSTORM + m];
    int y = idx / WV, x = idx % WV;
    int yf = y >> 2; if (yf > HF - 1) yf = HF - 1;
    int xf = x >> 2; if (xf > WF - 1) xf = WF - 1;
    int lin = yf * WF + xf;

    __shared__ float g[NC];
    g[tid] = features[((size_t)b * NC + tid) * (HF * WF) + lin];
    __syncthreads();

    float acc = 0.f;
    const float* wr = proj_w + (size_t)tid * NC;
    #pragma unroll 8
    for (int c = 0; c < NC; ++c) acc += g[c] * wr[c];

    out[((size_t)b * NSTORM + m) * NC + tid] = vld ? (acc + proj_b[tid]) : 0.f;
}

extern "C" void kernel_launch(void* const* d_in, const int* in_sizes, int n_in,
                              void* d_out, int out_size, void* d_ws, size_t ws_size,
                              hipStream_t stream) {
    const float* features = (const float*)d_in[0];
    const float* vil      = (const float*)d_in[1];
    const float* proj_w   = (const float*)d_in[2];
    const float* proj_b   = (const float*)d_in[3];
    float* out = (float*)d_out;

    uint8_t* ws = (uint8_t*)d_ws;
    int* tcnt      = (int*)ws;                        // 32*72 ints, all written
    int* sel_idx   = (int*)(ws + 16384);              // 1600 ints
    int* sel_valid = (int*)(ws + 16384 + NB * NSTORM * sizeof(int));
    uint64_t* cand = (uint64_t*)(ws + 32768);         // 32*72*256 u64 = 4.7 MB

    dim3 gA(GX, GY, NB);                   // 6 x 12 x 32
    peak_kernel<<<gA, 256, 0, stream>>>(vil, cand, tcnt);
    select_kernel<<<NB, 256, 0, stream>>>(cand, tcnt, vil, sel_idx, sel_valid, out);
    project_kernel<<<NB * NSTORM, 128, 0, stream>>>(features, proj_w, proj_b,
                                                    sel_idx, sel_valid, out);
}

// Round 7
// 73.919 us; speedup vs baseline: 4.5790x; 4.5790x over previous
//
#include <hip/hip_runtime.h>
#include <stdint.h>

#define HV 384
#define WV 384
#define HF 96
#define WF 96
#define NC 128
#define NB 32
#define NSTORM 50
#define TFRAMES 12
#define MIN_INT 0.3f

// peak tile geometry
#define TW 64
#define TH 32
#define GX (WV / TW)          // 6
#define GY (HV / TH)          // 12
#define GT (GX * GY)          // 72 tiles per batch
#define LCAP 256              // >= max real peaks per tile (~60 observed)

// selection: n ~= 2304 expected (147456/64). Fast path must cover it!
#define SELCAP 4096
#define SSZ 16                // keys per chunk
#define CSTR 17               // chunk stride in u64 (16 + pad -> 2-way LDS aliasing, free)

__device__ __forceinline__ int reflect_idx(int g, int n) {
    if (g < 0) return -g - 1;
    if (g >= n) return 2 * n - 1 - g;
    return g;
}

// ---- slow scalar peak predicate, used only on the dead fallback path
__device__ __forceinline__ bool is_peak(const float* __restrict__ vb, int p) {
    int i = p / WV, j = p % WV;
    float v = vb[p];
    if (!(v > MIN_INT)) return false;
    for (int dr = -4; dr <= 3; ++dr) {
        const float* row = vb + reflect_idx(i + dr, HV) * WV;
        for (int dc = -4; dc <= 3; ++dc)
            if (row[reflect_idx(j + dc, WV)] > v) return false;
    }
    return true;
}

// ---- kernel 1: separable 8x8 max filter on LDS tiles; float4 staging;
// per-tile candidate slots (no global atomics, no memset — every tcnt slot
// is written every launch). key = (float_bits(v) << 32) | ~idx — strict
// total order -> deterministic selection regardless of compaction order.
__global__ void peak_kernel(const float* __restrict__ vil,
                            uint64_t* __restrict__ cand,
                            int* __restrict__ tcnt) {
    __shared__ __align__(16) float A[TH + 7][TW + 8];  // tile + halo
    __shared__ float Bm[TH + 7][TW];                   // horizontal max
    __shared__ uint64_t lkeys[LCAP];
    __shared__ int lcnt;

    int b = blockIdx.z, bx = blockIdx.x;
    int tx0 = bx * TW, ty0 = blockIdx.y * TH;
    int tile = blockIdx.y * GX + bx;
    int tid = threadIdx.x;                 // 256 threads
    const float* vb = vil + ((size_t)b * TFRAMES + (TFRAMES - 1)) * (HV * WV);

    if (tid == 0) lcnt = 0;

    // float4 staging; row reflect is pointer-only, keeps 16B alignment.
    int c0   = (bx == 0) ? 0 : tx0 - 4;               // multiple of 4
    int nf4  = (bx == 0 || bx == GX - 1) ? 17 : 18;
    int aoff = c0 - (tx0 - 4);                        // 0 or 4
    for (int k = tid; k < (TH + 7) * nf4; k += 256) {
        int r = k / nf4, q = k - r * nf4;
        int gr = reflect_idx(ty0 + r - 4, HV);
        float4 vv = *(const float4*)(vb + (size_t)gr * WV + c0 + 4 * q);
        *(float4*)&A[r][aoff + 4 * q] = vv;
    }
    int nl = aoff;
    int rstart = aoff + 4 * nf4;
    int nr = 71 - rstart; if (nr < 0) nr = 0;
    int ns = nl + nr;
    if (ns) for (int k = tid; k < (TH + 7) * ns; k += 256) {
        int r = k / ns, s = k - r * ns;
        int c = (s < nl) ? s : rstart + (s - nl);
        int gr = reflect_idx(ty0 + r - 4, HV);
        int gc = reflect_idx(tx0 + c - 4, WV);
        A[r][c] = vb[(size_t)gr * WV + gc];
    }
    __syncthreads();

    // horizontal: Bm[r][c] = max(A[r][c..c+7])
    for (int k = tid; k < (TH + 7) * TW; k += 256) {
        int r = k / TW, c = k % TW;
        float m = A[r][c];
        #pragma unroll
        for (int d = 1; d < 8; ++d) m = fmaxf(m, A[r][c + d]);
        Bm[r][c] = m;
    }
    __syncthreads();

    // vertical + predicate
    for (int k = tid; k < TH * TW; k += 256) {
        int r = k / TW, c = k % TW;
        float v = A[r + 4][c + 4];
        if (v > MIN_INT) {
            float m = Bm[r][c];
            #pragma unroll
            for (int d = 1; d < 8; ++d) m = fmaxf(m, Bm[r + d][c]);
            if (m <= v) {                  // window max == v -> peak
                int p = (ty0 + r) * WV + (tx0 + c);
                uint64_t key = ((uint64_t)__float_as_uint(v) << 32)
                             | (uint64_t)(0xFFFFFFFFu - (uint32_t)p);
                int pos = atomicAdd(&lcnt, 1);        // LDS atomic only
                if (pos < LCAP) lkeys[pos] = key;
            }
        }
    }
    __syncthreads();

    int take = lcnt < LCAP ? lcnt : LCAP;
    if (tid == 0) tcnt[b * GT + tile] = take;
    uint64_t* dst = cand + (size_t)(b * GT + tile) * LCAP;
    for (int k = tid; k < take; k += 256) dst[k] = lkeys[k];
}

// ---- kernel 2: per batch, top-50 (desc value, ties -> lower idx).
// Parallel scan of 72 tile counts; compact all keys into padded LDS chunks
// (one binary search per key, once); each thread insertion-sorts its own
// 16-key chunk IN PLACE; single-wave 256-way merge pops the top-50.
// Also emits node_positions and valid.
__global__ void select_kernel(const uint64_t* __restrict__ cand,
                              const int* __restrict__ tcnt,
                              const float* __restrict__ vil,
                              int* __restrict__ sel_idx,
                              int* __restrict__ sel_valid,
                              float* __restrict__ out) {
    __shared__ uint64_t keysP[256 * CSTR];     // 34.8 KB padded chunks
    __shared__ int sc[128];
    __shared__ int offs[GT + 1];
    __shared__ int sel_idx_s[NSTORM];
    __shared__ int sel_valid_s[NSTORM];
    __shared__ uint64_t wred[4];
    __shared__ uint64_t bcast;

    int b = blockIdx.x;
    int tid = threadIdx.x;                     // 256
    const uint64_t* cb = cand + (size_t)b * GT * LCAP;

    // Hillis-Steele inclusive scan of 72 counts (padded to 128)
    int cval = (tid < GT) ? tcnt[b * GT + tid] : 0;
    if (tid < 128) sc[tid] = cval;
    __syncthreads();
    #pragma unroll
    for (int off = 1; off < 128; off <<= 1) {
        int v = 0;
        if (tid < 128 && tid >= off) v = sc[tid - off];
        __syncthreads();
        if (tid < 128) sc[tid] += v;
        __syncthreads();
    }
    if (tid == 0) offs[0] = 0;
    if (tid < GT) offs[tid + 1] = sc[tid];
    __syncthreads();
    int n = offs[GT];
    int K = n < NSTORM ? n : NSTORM;

    if (n <= SELCAP) {
        // zero-fill sentinels, then compact keys into padded chunk slots
        for (int k = tid; k < 256 * CSTR; k += 256) keysP[k] = 0;
        __syncthreads();
        for (int gi = tid; gi < n; gi += 256) {
            int lo = 0, hi = GT;
            while (hi - lo > 1) { int mid = (lo + hi) >> 1;
                                  if (offs[mid] <= gi) lo = mid; else hi = mid; }
            keysP[(gi >> 4) * CSTR + (gi & 15)] =
                cb[(size_t)lo * LCAP + (gi - offs[lo])];
        }
        __syncthreads();
        // in-place descending insertion sort of my own chunk
        {
            int base = tid * CSTR;
            for (int a = 1; a < SSZ; ++a) {
                uint64_t key = keysP[base + a];
                int j = a - 1;
                while (j >= 0 && keysP[base + j] < key) {
                    keysP[base + j + 1] = keysP[base + j]; --j;
                }
                keysP[base + j + 1] = key;
            }
        }
        __syncthreads();
        // single-wave 256-way merge: lane owns 4 chunks; keys unique, 0=sentinel
        if (tid < 64) {
            uint64_t v[4]; int h[4];
            #pragma unroll
            for (int i = 0; i < 4; ++i) { h[i] = 0; v[i] = keysP[(tid * 4 + i) * CSTR]; }
            for (int t = 0; t < K; ++t) {
                uint64_t best = v[0];
                #pragma unroll
                for (int i = 1; i < 4; ++i) if (v[i] > best) best = v[i];
                #pragma unroll
                for (int off = 32; off > 0; off >>= 1) {
                    uint64_t o = __shfl_xor(best, off);
                    if (o > best) best = o;
                }
                #pragma unroll
                for (int i = 0; i < 4; ++i) {
                    if (v[i] == best) {
                        ++h[i];
                        v[i] = (h[i] < SSZ) ? keysP[(tid * 4 + i) * CSTR + h[i]] : 0;
                    }
                }
                if (tid == 0) {
                    sel_idx_s[t] = (int)(~(uint32_t)(best & 0xFFFFFFFFu));
                    sel_valid_s[t] = 1;
                }
            }
        }
    } else {
        // safety path (n > 4096, dead for this data): iterative rescan
        uint64_t prev = ~0ull;
        for (int t = 0; t < K; ++t) {
            uint64_t best = 0;
            for (int gi = tid; gi < n; gi += 256) {
                int lo = 0, hi = GT;
                while (hi - lo > 1) { int mid = (lo + hi) >> 1;
                                      if (offs[mid] <= gi) lo = mid; else hi = mid; }
                uint64_t key = cb[(size_t)lo * LCAP + (gi - offs[lo])];
                if (key < prev && key > best) best = key;
            }
            #pragma unroll
            for (int off = 32; off > 0; off >>= 1) {
                uint64_t o = __shfl_xor(best, off);
                if (o > best) best = o;
            }
            if ((tid & 63) == 0) wred[tid >> 6] = best;
            __syncthreads();
            if (tid == 0) {
                uint64_t w = wred[0];
                #pragma unroll
                for (int i = 1; i < 4; ++i) if (wred[i] > w) w = wred[i];
                bcast = w;
                sel_idx_s[t] = (int)(~(uint32_t)(w & 0xFFFFFFFFu));
                sel_valid_s[t] = 1;
            }
            __syncthreads();
            prev = bcast;
        }
    }
    __syncthreads();

    // dead fallback: <50 peaks -> ascending non-peak indices; none -> center
    if (tid == 0 && K < NSTORM) {
        const float* vb = vil + ((size_t)b * TFRAMES + (TFRAMES - 1)) * (HV * WV);
        int f = 0;
        for (int t = K; t < NSTORM; ++t) {
            while (f < HV * WV && is_peak(vb, f)) ++f;
            sel_idx_s[t] = f; sel_valid_s[t] = 0; ++f;
        }
        if (n == 0) { sel_idx_s[0] = (HV / 2) * WV + (WV / 2); sel_valid_s[0] = 1; }
    }
    __syncthreads();

    if (tid < NSTORM) {
        int idx = sel_idx_s[tid], vld = sel_valid_s[tid];
        sel_idx[b * NSTORM + tid] = idx;
        sel_valid[b * NSTORM + tid] = vld;
        int y = idx / WV, x = idx % WV;
        int yf = y >> 2; if (yf > HF - 1) yf = HF - 1;
        int xf = x >> 2; if (xf > WF - 1) xf = WF - 1;
        float* pos_out   = out + (size_t)NB * NSTORM * NC;
        float* valid_out = pos_out + (size_t)NB * NSTORM * 2;
        pos_out[(b * NSTORM + tid) * 2 + 0] = (float)yf;
        pos_out[(b * NSTORM + tid) * 2 + 1] = (float)xf;
        valid_out[b * NSTORM + tid] = vld ? 1.f : 0.f;
    }
}

// ---- kernel 3: gather feature column + 128x128 matvec + bias (1600 blocks)
__global__ void project_kernel(const float* __restrict__ features,
                               const float* __restrict__ proj_w,
                               const float* __restrict__ proj_b,
                               const int* __restrict__ sel_idx,
                               const int* __restrict__ sel_valid,
                               float* __restrict__ out) {
    int blk = blockIdx.x;
    int b = blk / NSTORM;
    int m = blk % NSTORM;
    int tid = threadIdx.x;                 // 0..127

    int idx = sel_idx[b * NSTORM + m];
    int vld = sel_valid[b * NSTORM + m];
    int y = idx / WV, x = idx % WV;
    int yf = y >> 2; if (yf > HF - 1) yf = HF - 1;
    int xf = x >> 2; if (xf > WF - 1) xf = WF - 1;
    int lin = yf * WF + xf;

    __shared__ float g[NC];
    g[tid] = features[((size_t)b * NC + tid) * (HF * WF) + lin];
    __syncthreads();

    float acc = 0.f;
    const float* wr = proj_w + (size_t)tid * NC;
    #pragma unroll 8
    for (int c = 0; c < NC; ++c) acc += g[c] * wr[c];

    out[((size_t)b * NSTORM + m) * NC + tid] = vld ? (acc + proj_b[tid]) : 0.f;
}

extern "C" void kernel_launch(void* const* d_in, const int* in_sizes, int n_in,
                              void* d_out, int out_size, void* d_ws, size_t ws_size,
                              hipStream_t stream) {
    const float* features = (const float*)d_in[0];
    const float* vil      = (const float*)d_in[1];
    const float* proj_w   = (const float*)d_in[2];
    const float* proj_b   = (const float*)d_in[3];
    float* out = (float*)d_out;

    uint8_t* ws = (uint8_t*)d_ws;
    int* tcnt      = (int*)ws;                        // 32*72 ints, all written
    int* sel_idx   = (int*)(ws + 16384);              // 1600 ints
    int* sel_valid = (int*)(ws + 16384 + NB * NSTORM * sizeof(int));
    uint64_t* cand = (uint64_t*)(ws + 32768);         // 32*72*256 u64 = 4.7 MB

    dim3 gA(GX, GY, NB);                   // 6 x 12 x 32
    peak_kernel<<<gA, 256, 0, stream>>>(vil, cand, tcnt);
    select_kernel<<<NB, 256, 0, stream>>>(cand, tcnt, vil, sel_idx, sel_valid, out);
    project_kernel<<<NB * NSTORM, 128, 0, stream>>>(features, proj_w, proj_b,
                                                    sel_idx, sel_valid, out);
}

// Round 8
// 71.846 us; speedup vs baseline: 4.7112x; 1.0289x over previous
//
#include <hip/hip_runtime.h>
#include <stdint.h>

#define HV 384
#define WV 384
#define HF 96
#define WF 96
#define NC 128
#define NB 32
#define NSTORM 50
#define TFRAMES 12
#define MIN_INT 0.3f

// peak tile geometry
#define TW 64
#define TH 32
#define GX (WV / TW)          // 6
#define GY (HV / TH)          // 12
#define GT (GX * GY)          // 72 tiles per batch
#define LCAP 256              // >= provable max peaks per tile (~153)

// selection
#define CCAP 1024             // collect buffer (expected ~80 used)

__device__ __forceinline__ int reflect_idx(int g, int n) {
    if (g < 0) return -g - 1;
    if (g >= n) return 2 * n - 1 - g;
    return g;
}

// ---- slow scalar peak predicate, used only on the dead fallback path
__device__ __forceinline__ bool is_peak(const float* __restrict__ vb, int p) {
    int i = p / WV, j = p % WV;
    float v = vb[p];
    if (!(v > MIN_INT)) return false;
    for (int dr = -4; dr <= 3; ++dr) {
        const float* row = vb + reflect_idx(i + dr, HV) * WV;
        for (int dc = -4; dc <= 3; ++dc)
            if (row[reflect_idx(j + dc, WV)] > v) return false;
    }
    return true;
}

// ---- kernel 1: separable 8x8 max filter on LDS tiles; float4 staging;
// per-tile candidate slots (no global atomics, no memset — every tcnt slot
// is written every launch). key = (float_bits(v) << 32) | ~idx — strict
// total order -> deterministic selection regardless of compaction order.
__global__ void peak_kernel(const float* __restrict__ vil,
                            uint64_t* __restrict__ cand,
                            int* __restrict__ tcnt) {
    __shared__ __align__(16) float A[TH + 7][TW + 8];  // tile + halo
    __shared__ float Bm[TH + 7][TW];                   // horizontal max
    __shared__ uint64_t lkeys[LCAP];
    __shared__ int lcnt;

    int b = blockIdx.z, bx = blockIdx.x;
    int tx0 = bx * TW, ty0 = blockIdx.y * TH;
    int tile = blockIdx.y * GX + bx;
    int tid = threadIdx.x;                 // 256 threads
    const float* vb = vil + ((size_t)b * TFRAMES + (TFRAMES - 1)) * (HV * WV);

    if (tid == 0) lcnt = 0;

    // float4 staging; row reflect is pointer-only, keeps 16B alignment.
    int c0   = (bx == 0) ? 0 : tx0 - 4;               // multiple of 4
    int nf4  = (bx == 0 || bx == GX - 1) ? 17 : 18;
    int aoff = c0 - (tx0 - 4);                        // 0 or 4
    for (int k = tid; k < (TH + 7) * nf4; k += 256) {
        int r = k / nf4, q = k - r * nf4;
        int gr = reflect_idx(ty0 + r - 4, HV);
        float4 vv = *(const float4*)(vb + (size_t)gr * WV + c0 + 4 * q);
        *(float4*)&A[r][aoff + 4 * q] = vv;
    }
    int nl = aoff;
    int rstart = aoff + 4 * nf4;
    int nr = 71 - rstart; if (nr < 0) nr = 0;
    int ns = nl + nr;
    if (ns) for (int k = tid; k < (TH + 7) * ns; k += 256) {
        int r = k / ns, s = k - r * ns;
        int c = (s < nl) ? s : rstart + (s - nl);
        int gr = reflect_idx(ty0 + r - 4, HV);
        int gc = reflect_idx(tx0 + c - 4, WV);
        A[r][c] = vb[(size_t)gr * WV + gc];
    }
    __syncthreads();

    // horizontal: Bm[r][c] = max(A[r][c..c+7])
    for (int k = tid; k < (TH + 7) * TW; k += 256) {
        int r = k / TW, c = k % TW;
        float m = A[r][c];
        #pragma unroll
        for (int d = 1; d < 8; ++d) m = fmaxf(m, A[r][c + d]);
        Bm[r][c] = m;
    }
    __syncthreads();

    // vertical + predicate
    for (int k = tid; k < TH * TW; k += 256) {
        int r = k / TW, c = k % TW;
        float v = A[r + 4][c + 4];
        if (v > MIN_INT) {
            float m = Bm[r][c];
            #pragma unroll
            for (int d = 1; d < 8; ++d) m = fmaxf(m, Bm[r + d][c]);
            if (m <= v) {                  // window max == v -> peak
                int p = (ty0 + r) * WV + (tx0 + c);
                uint64_t key = ((uint64_t)__float_as_uint(v) << 32)
                             | (uint64_t)(0xFFFFFFFFu - (uint32_t)p);
                int pos = atomicAdd(&lcnt, 1);        // LDS atomic only
                if (pos < LCAP) lkeys[pos] = key;
            }
        }
    }
    __syncthreads();

    int take = lcnt < LCAP ? lcnt : LCAP;
    if (tid == 0) tcnt[b * GT + tile] = take;
    uint64_t* dst = cand + (size_t)(b * GT + tile) * LCAP;
    for (int k = tid; k < take; k += 256) dst[k] = lkeys[k];
}

// ---- kernel 2: per batch, top-50 (desc value, ties -> lower idx) via
// 256-bin histogram on the value's top float bits (monotone in key):
// pass1 histogram -> suffix scan finds threshold bin B* containing rank-50
// -> pass2 collects keys with bin >= B* (expected ~80) -> m^2 ranking
// writes each winner straight to its rank. O(n) trivial work, no sorts,
// no dependent LDS chains. Also emits node_positions and valid.
__global__ void select_kernel(const uint64_t* __restrict__ cand,
                              const int* __restrict__ tcnt,
                              const float* __restrict__ vil,
                              int* __restrict__ sel_idx,
                              int* __restrict__ sel_valid,
                              float* __restrict__ out) {
    __shared__ uint64_t coll[CCAP];            // 8 KB
    __shared__ int hist[256];
    __shared__ int rss[256];                   // reversed suffix scan
    __shared__ int sc[128];
    __shared__ int offs[GT + 1];
    __shared__ int sel_idx_s[NSTORM];
    __shared__ int sel_valid_s[NSTORM];
    __shared__ int jstar_s, ccnt;
    __shared__ uint64_t wred[4];
    __shared__ uint64_t bcast;

    int b = blockIdx.x;
    int tid = threadIdx.x;                     // 256
    const uint64_t* cb = cand + (size_t)b * GT * LCAP;

    // Hillis-Steele inclusive scan of 72 tile counts (padded to 128)
    int cval = (tid < GT) ? tcnt[b * GT + tid] : 0;
    if (tid < 128) sc[tid] = cval;
    hist[tid] = 0;
    if (tid == 0) ccnt = 0;
    __syncthreads();
    #pragma unroll
    for (int off = 1; off < 128; off <<= 1) {
        int v = 0;
        if (tid < 128 && tid >= off) v = sc[tid - off];
        __syncthreads();
        if (tid < 128) sc[tid] += v;
        __syncthreads();
    }
    if (tid == 0) offs[0] = 0;
    if (tid < GT) offs[tid + 1] = sc[tid];
    __syncthreads();
    int n = offs[GT];
    int target = n < NSTORM ? n : NSTORM;

    if (n > 0) {
        // pass 1: histogram of top-16-bit value bins
        for (int gi = tid; gi < n; gi += 256) {
            int lo = 0, hi = GT;
            while (hi - lo > 1) { int mid = (lo + hi) >> 1;
                                  if (offs[mid] <= gi) lo = mid; else hi = mid; }
            uint64_t key = cb[(size_t)lo * LCAP + (gi - offs[lo])];
            int bin = (int)(uint32_t)((key >> 48)) - 0x3E99;
            bin = (bin < 0) ? 0 : (bin > 255 ? 255 : bin);
            atomicAdd(&hist[bin], 1);
        }
        __syncthreads();
        // suffix counts: S[j] = # keys with bin >= j  (S = rss reversed)
        rss[tid] = hist[255 - tid];
        __syncthreads();
        #pragma unroll
        for (int off = 1; off < 256; off <<= 1) {
            int v = (tid >= off) ? rss[tid - off] : 0;
            __syncthreads();
            rss[tid] += v;
            __syncthreads();
        }
        {   // j* = max j with S[j] >= target
            int S_j  = rss[255 - tid];
            int S_j1 = (tid == 255) ? 0 : rss[254 - tid];
            if (S_j >= target && S_j1 < target) jstar_s = tid;
        }
        __syncthreads();
        int jstar = jstar_s;
        // pass 2: collect keys in bins >= j*
        for (int gi = tid; gi < n; gi += 256) {
            int lo = 0, hi = GT;
            while (hi - lo > 1) { int mid = (lo + hi) >> 1;
                                  if (offs[mid] <= gi) lo = mid; else hi = mid; }
            uint64_t key = cb[(size_t)lo * LCAP + (gi - offs[lo])];
            int bin = (int)(uint32_t)((key >> 48)) - 0x3E99;
            bin = (bin < 0) ? 0 : (bin > 255 ? 255 : bin);
            if (bin >= jstar) {
                int pos = atomicAdd(&ccnt, 1);
                if (pos < CCAP) coll[pos] = key;
            }
        }
        __syncthreads();
        int m = ccnt < CCAP ? ccnt : CCAP;

        if (ccnt <= CCAP) {
            // rank each collected key (keys unique -> unique ranks)
            for (int i = tid; i < m; i += 256) {
                uint64_t ki = coll[i];
                int r = 0;
                for (int j = 0; j < m; ++j) r += (coll[j] > ki);
                if (r < target) {
                    sel_idx_s[r] = (int)(~(uint32_t)(ki & 0xFFFFFFFFu));
                    sel_valid_s[r] = 1;
                }
            }
        } else {
            // dead safety path (bin overflow): iterative rescan
            uint64_t prev = ~0ull;
            for (int t = 0; t < target; ++t) {
                uint64_t best = 0;
                for (int gi = tid; gi < n; gi += 256) {
                    int lo = 0, hi = GT;
                    while (hi - lo > 1) { int mid = (lo + hi) >> 1;
                                          if (offs[mid] <= gi) lo = mid; else hi = mid; }
                    uint64_t key = cb[(size_t)lo * LCAP + (gi - offs[lo])];
                    if (key < prev && key > best) best = key;
                }
                #pragma unroll
                for (int off = 32; off > 0; off >>= 1) {
                    uint64_t o = __shfl_xor(best, off);
                    if (o > best) best = o;
                }
                if ((tid & 63) == 0) wred[tid >> 6] = best;
                __syncthreads();
                if (tid == 0) {
                    uint64_t w = wred[0];
                    #pragma unroll
                    for (int i = 1; i < 4; ++i) if (wred[i] > w) w = wred[i];
                    bcast = w;
                    sel_idx_s[t] = (int)(~(uint32_t)(w & 0xFFFFFFFFu));
                    sel_valid_s[t] = 1;
                }
                __syncthreads();
                prev = bcast;
            }
        }
    }
    __syncthreads();

    // dead fallback: <50 peaks -> ascending non-peak indices; none -> center
    if (tid == 0 && target < NSTORM) {
        const float* vb = vil + ((size_t)b * TFRAMES + (TFRAMES - 1)) * (HV * WV);
        int f = 0;
        for (int t = target; t < NSTORM; ++t) {
            while (f < HV * WV && is_peak(vb, f)) ++f;
            sel_idx_s[t] = f; sel_valid_s[t] = 0; ++f;
        }
        if (n == 0) { sel_idx_s[0] = (HV / 2) * WV + (WV / 2); sel_valid_s[0] = 1; }
    }
    __syncthreads();

    if (tid < NSTORM) {
        int idx = sel_idx_s[tid], vld = sel_valid_s[tid];
        sel_idx[b * NSTORM + tid] = idx;
        sel_valid[b * NSTORM + tid] = vld;
        int y = idx / WV, x = idx % WV;
        int yf = y >> 2; if (yf > HF - 1) yf = HF - 1;
        int xf = x >> 2; if (xf > WF - 1) xf = WF - 1;
        float* pos_out   = out + (size_t)NB * NSTORM * NC;
        float* valid_out = pos_out + (size_t)NB * NSTORM * 2;
        pos_out[(b * NSTORM + tid) * 2 + 0] = (float)yf;
        pos_out[(b * NSTORM + tid) * 2 + 1] = (float)xf;
        valid_out[b * NSTORM + tid] = vld ? 1.f : 0.f;
    }
}

// ---- kernel 3: gather + 128x128 matvec + bias; 5 storms per block
// (amortizes the proj_w row read 5x; order-preserving accumulation).
#define SPB 5
__global__ void project_kernel(const float* __restrict__ features,
                               const float* __restrict__ proj_w,
                               const float* __restrict__ proj_b,
                               const int* __restrict__ sel_idx,
                               const int* __restrict__ sel_valid,
                               float* __restrict__ out) {
    int blk = blockIdx.x;                  // [0, NB * NSTORM/SPB)
    int b = blk / (NSTORM / SPB);
    int grp = blk % (NSTORM / SPB);
    int tid = threadIdx.x;                 // 0..127

    __shared__ __align__(16) float g[SPB][NC];
    __shared__ int idxs[SPB], vlds[SPB];

    if (tid < SPB) {
        int m = grp * SPB + tid;
        idxs[tid] = sel_idx[b * NSTORM + m];
        vlds[tid] = sel_valid[b * NSTORM + m];
    }
    __syncthreads();

    for (int q = tid; q < SPB * NC; q += 128) {
        int s = q >> 7, c = q & 127;
        int idx = idxs[s];
        int y = idx / WV, x = idx % WV;
        int yf = y >> 2; if (yf > HF - 1) yf = HF - 1;
        int xf = x >> 2; if (xf > WF - 1) xf = WF - 1;
        g[s][c] = features[((size_t)b * NC + c) * (HF * WF) + yf * WF + xf];
    }
    __syncthreads();

    int d = tid;
    const float4* w4 = (const float4*)(proj_w + (size_t)d * NC);
    float acc[SPB] = {0.f, 0.f, 0.f, 0.f, 0.f};
    for (int q = 0; q < 32; ++q) {
        float4 wv = w4[q];
        #pragma unroll
        for (int s = 0; s < SPB; ++s) {
            float4 gv = *(const float4*)&g[s][4 * q];
            acc[s] += gv.x * wv.x;
            acc[s] += gv.y * wv.y;
            acc[s] += gv.z * wv.z;
            acc[s] += gv.w * wv.w;
        }
    }
    float bias = proj_b[d];
    #pragma unroll
    for (int s = 0; s < SPB; ++s) {
        int m = grp * SPB + s;
        out[((size_t)b * NSTORM + m) * NC + d] = vlds[s] ? (acc[s] + bias) : 0.f;
    }
}

extern "C" void kernel_launch(void* const* d_in, const int* in_sizes, int n_in,
                              void* d_out, int out_size, void* d_ws, size_t ws_size,
                              hipStream_t stream) {
    const float* features = (const float*)d_in[0];
    const float* vil      = (const float*)d_in[1];
    const float* proj_w   = (const float*)d_in[2];
    const float* proj_b   = (const float*)d_in[3];
    float* out = (float*)d_out;

    uint8_t* ws = (uint8_t*)d_ws;
    int* tcnt      = (int*)ws;                        // 32*72 ints, all written
    int* sel_idx   = (int*)(ws + 16384);              // 1600 ints
    int* sel_valid = (int*)(ws + 16384 + NB * NSTORM * sizeof(int));
    uint64_t* cand = (uint64_t*)(ws + 32768);         // 32*72*256 u64 = 4.7 MB

    dim3 gA(GX, GY, NB);                   // 6 x 12 x 32
    peak_kernel<<<gA, 256, 0, stream>>>(vil, cand, tcnt);
    select_kernel<<<NB, 256, 0, stream>>>(cand, tcnt, vil, sel_idx, sel_valid, out);
    project_kernel<<<NB * (NSTORM / SPB), 128, 0, stream>>>(features, proj_w, proj_b,
                                                            sel_idx, sel_valid, out);
}